// Round 4
// baseline (154.113 us; speedup 1.0000x reference)
//
#include <hip/hip_runtime.h>

// YOLOv3 loss: B=32, A=3, S=52, C=80
constexpr int Aa = 3, Ss = 52, Cc = 80;
constexpr int NCELL = 32 * Aa * Ss * Ss;                 // 259584
constexpr int PSTR  = 5 + Cc;                            // 85 floats per cell
constexpr unsigned NP4 = (unsigned)NCELL * PSTR / 4u;    // 5,516,160 float4s (exact)
constexpr float L_CLASS = 1.0f, L_NOOBJ = 10.0f, L_OBJ = 1.0f, L_BOX = 10.0f;

// ws layout (4B words): [0..5] float accs ([1]=n_noobj,[2]=noobj_sum,[3]=obj_sum,
// [4]=box_sum,[5]=cls_sum), [6]=obj_count (uint), [7] pad, [8..] obj cell list (uint)

__device__ __forceinline__ float bce0(float x) {        // bce(x, 0)
    return fmaxf(x, 0.0f) + log1pf(expf(-fabsf(x)));
}

// --- K1: coalesced stream of predictions; extract p0 lanes, compact obj cells ---
__global__ void __launch_bounds__(256) yolo_stream(const float4* __restrict__ pred4,
                                                   const float* __restrict__ tgt,
                                                   float* __restrict__ acc,
                                                   unsigned* __restrict__ cnt,
                                                   unsigned* __restrict__ list,
                                                   unsigned cap) {
    float a_no = 0.f, a_nn = 0.f;
    const unsigned stride = gridDim.x * blockDim.x;
    const unsigned tid = blockIdx.x * blockDim.x + threadIdx.x;

    for (unsigned j = tid; j < NP4; j += 2u * stride) {
        const unsigned j2 = j + stride;
        const bool has2 = (j2 < NP4);
        float4 v = pred4[j];                       // two independent loads in flight
        float4 w = has2 ? pred4[j2] : make_float4(0.f, 0.f, 0.f, 0.f);

        #pragma unroll
        for (int half = 0; half < 2; ++half) {
            if (half == 1 && !has2) break;
            const float4 u = (half == 0) ? v : w;
            const unsigned f0 = 4u * ((half == 0) ? j : j2);
            const unsigned cell = f0 / 85u;        // magic-mul
            const unsigned r = f0 - cell * 85u;
            float p0 = u.x;
            unsigned oc = cell;
            bool hit = true;
            if (r == 0u)       { /* p0 = u.x, oc = cell */ }
            else if (r == 84u) { p0 = u.y; oc = cell + 1u; }
            else if (r == 83u) { p0 = u.z; oc = cell + 1u; }
            else if (r == 82u) { p0 = u.w; oc = cell + 1u; }
            else hit = false;

            if (hit) {
                const float t0 = tgt[oc * 6u];
                if (t0 == 0.0f) {
                    a_nn += 1.0f;
                    a_no += bce0(p0);
                } else if (t0 == 1.0f) {
                    const unsigned s = atomicAdd(cnt, 1u);
                    if (s < cap) list[s] = oc;
                }
            }
        }
    }

    // wave reduce -> LDS -> 2 atomics per block
    #pragma unroll
    for (int off = 32; off > 0; off >>= 1) {
        a_no += __shfl_down(a_no, off, 64);
        a_nn += __shfl_down(a_nn, off, 64);
    }
    __shared__ float sdata[2][4];
    const int lane = threadIdx.x & 63, wid = threadIdx.x >> 6;
    if (lane == 0) { sdata[0][wid] = a_no; sdata[1][wid] = a_nn; }
    __syncthreads();
    if (threadIdx.x == 0) {
        float s0 = 0.f, s1 = 0.f;
        for (int wv = 0; wv < 4; ++wv) { s0 += sdata[0][wv]; s1 += sdata[1][wv]; }
        atomicAdd(&acc[2], s0);
        atomicAdd(&acc[1], s1);
    }
}

// --- K2: one wave per object cell from the worklist ---
__global__ void __launch_bounds__(256) yolo_obj(const float* __restrict__ pred,
                                                const float* __restrict__ tgt,
                                                const float* __restrict__ anchors,
                                                float* __restrict__ acc,
                                                const unsigned* __restrict__ cnt,
                                                const unsigned* __restrict__ list,
                                                unsigned cap) {
    const int lane = threadIdx.x & 63;
    const unsigned gw = (blockIdx.x * blockDim.x + threadIdx.x) >> 6;
    const unsigned nw = (gridDim.x * blockDim.x) >> 6;
    unsigned n = *cnt;
    if (n > cap) n = cap;

    float a_obj = 0.f, a_box = 0.f, a_cls = 0.f;

    for (unsigned i = gw; i < n; i += nw) {
        const unsigned cell = list[i];
        const float* p = pred + (size_t)cell * PSTR;
        const float* t = tgt + (size_t)cell * 6u;

        // 80 logits: lanes 0..63 -> c=lane; lanes 0..15 also -> c=64+lane
        float v0 = p[5 + lane];
        float v1 = (lane < 16) ? p[69 + lane] : -INFINITY;
        float mx = fmaxf(v0, v1);
        #pragma unroll
        for (int off = 32; off; off >>= 1) mx = fmaxf(mx, __shfl_xor(mx, off, 64));
        float e = expf(v0 - mx) + ((lane < 16) ? expf(v1 - mx) : 0.0f);
        #pragma unroll
        for (int off = 32; off; off >>= 1) e += __shfl_xor(e, off, 64);

        const int cls = (int)t[5];
        const float lc = (cls < 64) ? __shfl(v0, cls, 64) : __shfl(v1, cls - 64, 64);

        // wave-uniform scalar loads (broadcast)
        const float p0 = p[0], px = p[1], py = p[2], pw = p[3], ph = p[4];
        const float tx = t[1], ty = t[2], tw = t[3], th = t[4];
        const unsigned a = (cell / (unsigned)(Ss * Ss)) % (unsigned)Aa;
        const float ax = anchors[2 * a], ay = anchors[2 * a + 1];

        const float sx = 1.0f / (1.0f + expf(-px));
        const float sy = 1.0f / (1.0f + expf(-py));
        const float ew = expf(pw) * ax;
        const float eh = expf(ph) * ay;

        const float ax1 = sx - ew * 0.5f, ax2 = sx + ew * 0.5f;
        const float ay1 = sy - eh * 0.5f, ay2 = sy + eh * 0.5f;
        const float bx1 = tx - tw * 0.5f, bx2 = tx + tw * 0.5f;
        const float by1 = ty - th * 0.5f, by2 = ty + th * 0.5f;
        const float iw = fmaxf(fminf(ax2, bx2) - fmaxf(ax1, bx1), 0.0f);
        const float ih = fmaxf(fminf(ay2, by2) - fmaxf(ay1, by1), 0.0f);
        const float inter = iw * ih;
        const float area_a = fabsf((ax2 - ax1) * (ay2 - ay1));
        const float area_b = fabsf((bx2 - bx1) * (by2 - by1));
        const float iou = inter / (area_a + area_b - inter + 1e-6f);

        if (lane == 0) {
            a_cls += (mx + logf(e)) - lc;
            a_obj += fmaxf(p0, 0.0f) - p0 * iou + log1pf(expf(-fabsf(p0)));
            const float dx = sx - tx, dy = sy - ty;
            const float dw = pw - logf(tw / ax + 1e-16f);
            const float dh = ph - logf(th / ay + 1e-16f);
            a_box += dx * dx + dy * dy + dw * dw + dh * dh;
        }
    }

    // lane0-only partials -> LDS block reduce -> 3 atomics per block
    __shared__ float sdata[3][4];
    const int wid = threadIdx.x >> 6;
    if (lane == 0) { sdata[0][wid] = a_obj; sdata[1][wid] = a_box; sdata[2][wid] = a_cls; }
    __syncthreads();
    if (threadIdx.x == 0) {
        float s0 = 0.f, s1 = 0.f, s2 = 0.f;
        for (int wv = 0; wv < 4; ++wv) { s0 += sdata[0][wv]; s1 += sdata[1][wv]; s2 += sdata[2][wv]; }
        atomicAdd(&acc[3], s0);
        atomicAdd(&acc[4], s1);
        atomicAdd(&acc[5], s2);
    }
}

__global__ void yolo_final(const float* __restrict__ acc,
                           const unsigned* __restrict__ cnt,
                           float* __restrict__ out) {
    const float n_obj   = fmaxf((float)(*cnt), 1.0f);
    const float n_noobj = fmaxf(acc[1], 1.0f);
    out[0] = L_NOOBJ * acc[2] / n_noobj
           + L_OBJ   * acc[3] / n_obj
           + L_BOX   * acc[4] / (n_obj * 4.0f)
           + L_CLASS * acc[5] / n_obj;
}

extern "C" void kernel_launch(void* const* d_in, const int* in_sizes, int n_in,
                              void* d_out, int out_size, void* d_ws, size_t ws_size,
                              hipStream_t stream) {
    const float* pred = (const float*)d_in[0];
    const float* tgt  = (const float*)d_in[1];
    const float* anc  = (const float*)d_in[2];
    float* out = (float*)d_out;
    float* acc = (float*)d_ws;
    unsigned* cnt  = (unsigned*)d_ws + 6;
    unsigned* list = (unsigned*)d_ws + 8;
    const unsigned cap = (ws_size > 32) ? (unsigned)((ws_size - 32) / 4) : 0u;

    hipMemsetAsync(d_ws, 0, 32, stream);   // accs + count

    yolo_stream<<<2048, 256, 0, stream>>>((const float4*)pred, tgt, acc, cnt, list, cap);
    yolo_obj<<<512, 256, 0, stream>>>(pred, tgt, anc, acc, cnt, list, cap);
    yolo_final<<<1, 1, 0, stream>>>(acc, cnt, out);
}